// Round 16
// baseline (316.166 us; speedup 1.0000x reference)
//
#include <hip/hip_runtime.h>

#define N_NODES 50000
#define N_EDGES 500000
#define NUM_G   128
#define SCAN_NB 49               // ceil(50176/1024)
#define PN      (SCAN_NB * 1024) // 50176 padded node count
#define NCX     64               // edge chunks
#define ECH     7813             // 64*7813 >= 500000
#define RNG     8192             // nodes per LDS range (32 KB per array)
#define NRY     7                // 7*8192 >= PN
#define CONVB   7813             // conv blocks (50000*160/4 / 256)
#define WPREPB  360
#define SCVB    (NCX * NRY)      // 448 scatter virtual blocks
#define GEMM_MB 782              // (50000+63)/64

typedef __attribute__((ext_vector_type(8))) short short8;
typedef __attribute__((ext_vector_type(4))) float f32x4;

__device__ __forceinline__ unsigned f2bf(float x) {
    unsigned u = __float_as_uint(x);
    return (u + 0x7FFFu + ((u >> 16) & 1u)) >> 16;   // RNE
}
__device__ __forceinline__ float bf2f(unsigned h) {
    return __uint_as_float(h << 16);
}

// ============ D1: single-pass hist (deg by src + cnt by dst in one edge scan) ============
__global__ __launch_bounds__(256)
void hist_kernel(const int* __restrict__ src, const int* __restrict__ dst,
                 const float* __restrict__ ea,
                 float* __restrict__ pdeg, int* __restrict__ pcnt) {
    __shared__ float ldeg[RNG];   // 32 KB
    __shared__ int   lcnt[RNG];   // 32 KB
    int xk = blockIdx.x, y = blockIdx.y, tid = threadIdx.x;
    int base = y * RNG;
    for (int i = tid; i < RNG; i += 256) { ldeg[i] = 0.f; lcnt[i] = 0; }
    __syncthreads();
    int e0 = xk * ECH, e1 = min(e0 + ECH, N_EDGES);
    for (int e = e0 + tid; e < e1; e += 256) {
        int s = src[e], d = dst[e];
        float a = ea[e];
        if ((unsigned)(s - base) < RNG) atomicAdd(&ldeg[s - base], a);
        if ((unsigned)(d - base) < RNG) atomicAdd(&lcnt[d - base], 1);
    }
    __syncthreads();
    for (int i = tid; i < RNG; i += 256) {
        int n = base + i;
        if (n < PN) {
            pdeg[(size_t)xk * PN + n] = ldeg[i];
            pcnt[(size_t)xk * PN + n] = lcnt[i];
        }
    }
}

// ==== D2: reduce partials + fp32->bf16 conv + weight prep (one dispatch) ====
__device__ __forceinline__ void wprep_one(const float* __restrict__ W, unsigned short* __restrict__ WT,
                                          int t, int FIN, int F) {
    int n = t / FIN, k = t - n * FIN;
    int sel = n / F, c = n - sel * F;
    float v;
    if (sel == 0) v = W[(size_t)k * F + c] - W[(size_t)2 * FIN * F + (size_t)k * F + c];
    else          v = W[(size_t)sel * FIN * F + (size_t)k * F + c];
    WT[t] = (unsigned short)f2bf(v);
}

__global__ __launch_bounds__(256)
void rs_kernel(const float* __restrict__ pdeg, int* __restrict__ pcnt,
               float* __restrict__ dinv, int* __restrict__ cnt, int* __restrict__ partial,
               const float* __restrict__ x, unsigned short* __restrict__ Xb,
               const float* __restrict__ W1, const float* __restrict__ W2,
               const float* __restrict__ W3,
               unsigned short* __restrict__ WT1, unsigned short* __restrict__ WT2,
               unsigned short* __restrict__ WT3) {
    __shared__ int red[256];
    int vb = blockIdx.x, t = threadIdx.x;
    if (vb < SCAN_NB) {
        int b = vb;
        int i0 = b * 1024 + t * 4;
        float d0 = 0.f, d1 = 0.f, d2 = 0.f, d3 = 0.f;
        int r0 = 0, r1 = 0, r2 = 0, r3 = 0;
        for (int xk = 0; xk < NCX; ++xk) {
            float4 pv = *reinterpret_cast<const float4*>(pdeg + (size_t)xk * PN + i0);
            int4   cv = *reinterpret_cast<const int4*>(pcnt + (size_t)xk * PN + i0);
            *reinterpret_cast<int4*>(pcnt + (size_t)xk * PN + i0) = make_int4(r0, r1, r2, r3);
            d0 += pv.x; d1 += pv.y; d2 += pv.z; d3 += pv.w;
            r0 += cv.x; r1 += cv.y; r2 += cv.z; r3 += cv.w;
        }
        float dd[4] = {d0, d1, d2, d3};
        int   rr[4] = {r0, r1, r2, r3};
        int s = 0;
        #pragma unroll
        for (int j = 0; j < 4; ++j) {
            int n = i0 + j;
            if (n < N_NODES) {
                float dv = dd[j], r = 0.f;
                if (dv > 0.f) {
                    r = rsqrtf(dv);
                    r = r * (1.5f - 0.5f * dv * r * r);   // Newton refine to ~fp32 exact
                }
                dinv[n] = r;
                cnt[n] = rr[j];
                s += rr[j];
            } else {
                cnt[n] = 0;
            }
        }
        red[t] = s;
        __syncthreads();
        for (int off = 128; off > 0; off >>= 1) {
            if (t < off) red[t] += red[t + off];
            __syncthreads();
        }
        if (t == 0) partial[b] = red[0];
    } else if (vb < SCAN_NB + CONVB) {
        int tt = (vb - SCAN_NB) * 256 + t;
        if (tt < N_NODES * 160 / 4) {
            float4 v = reinterpret_cast<const float4*>(x)[tt];
            ushort4 r;
            r.x = (unsigned short)f2bf(v.x);
            r.y = (unsigned short)f2bf(v.y);
            r.z = (unsigned short)f2bf(v.z);
            r.w = (unsigned short)f2bf(v.w);
            *reinterpret_cast<ushort4*>(Xb + (size_t)tt * 4) = r;
        }
    } else {
        int tt = (vb - SCAN_NB - CONVB) * 256 + t;
        if (tt < 61440)      wprep_one(W1, WT1, tt, 160, 128);
        else if (tt < 86016) wprep_one(W2, WT2, tt - 61440, 128, 64);
        else if (tt < 92160) wprep_one(W3, WT3, tt - 86016, 64, 32);
    }
}

// ==== D3: final scan -> rowptr (each block redundantly wave-scans the 49 partials) ====
__global__ __launch_bounds__(256)
void scan_final_kernel(const int* __restrict__ cnt, const int* __restrict__ partial,
                       int* __restrict__ rowptr, int n) {
    int b = blockIdx.x, t = threadIdx.x;
    __shared__ int red[256];
    __shared__ int sh_off, sh_tot;
    if (t < 64) {
        int orig = (t < SCAN_NB) ? partial[t] : 0;
        int v = orig;
        #pragma unroll
        for (int off = 1; off < 64; off <<= 1) {
            int u = __shfl_up(v, off, 64);
            if (t >= off) v += u;
        }
        if (t == b) sh_off = v - orig;            // this block's exclusive offset (b < 49 <= 63)
        if (t == SCAN_NB - 1) sh_tot = v;         // grand total
    }
    __syncthreads();
    int4 v = reinterpret_cast<const int4*>(cnt)[b * 256 + t];
    int s = v.x + v.y + v.z + v.w;
    red[t] = s;
    __syncthreads();
    for (int off = 1; off < 256; off <<= 1) {
        int u = (t >= off) ? red[t - off] : 0;
        __syncthreads();
        red[t] += u;
        __syncthreads();
    }
    int excl = sh_off + ((t == 0) ? 0 : red[t - 1]);
    int i0 = b * 1024 + t * 4;
    if (i0 < n)     rowptr[i0]     = excl;
    if (i0 + 1 < n) rowptr[i0 + 1] = excl + v.x;
    if (i0 + 2 < n) rowptr[i0 + 2] = excl + v.x + v.y;
    if (i0 + 3 < n) rowptr[i0 + 3] = excl + v.x + v.y + v.z;
    if (b == SCAN_NB - 1 && t == 0) rowptr[n] = sh_tot;
}

// ==== shared bodies for the merged D4 dispatch ====
__device__ void scatter_body(int vb, const int* __restrict__ src, const int* __restrict__ dst,
                             const float* __restrict__ ea,
                             const int* __restrict__ rowptr, const int* __restrict__ pcnt,
                             int2* __restrict__ csr, unsigned char* smraw) {
    int* cursor = (int*)smraw;
    int tid = threadIdx.x;
    int x = vb & 63, y = vb >> 6;
    int base = y * RNG;
    for (int i = tid; i < RNG; i += 256) {
        int n = base + i;
        cursor[i] = (n < N_NODES) ? (rowptr[n] + pcnt[(size_t)x * PN + n]) : 0;
    }
    __syncthreads();
    int e0 = x * ECH, e1 = min(e0 + ECH, N_EDGES);
    for (int e = e0 + tid; e < e1; e += 256) {
        int d = dst[e];
        if ((unsigned)(d - base) < RNG) {
            int pos = atomicAdd(&cursor[d - base], 1);   // LDS atomic
            int2 ew;
            ew.x = src[e];
            ew.y = __float_as_int(ea[e]);
            csr[pos] = ew;
        }
    }
}

template<int FIN, int F>
__device__ void gemm_body(int bx, int g, const unsigned short* __restrict__ Xb,
                          const unsigned short* __restrict__ WT, const float* __restrict__ dinv,
                          unsigned short* __restrict__ Y0, unsigned short* __restrict__ Y1,
                          unsigned short* __restrict__ Y2, int nrows, unsigned char* smraw) {
    constexpr int KT = FIN / 32;
    constexpr int NT = F / 32;
    constexpr int SA = FIN + 8;
    constexpr int F8 = FIN / 8;
    short* Bs = (short*)smraw;

    int tid = threadIdx.x;
    int lane = tid & 63, w = tid >> 6;
    int m0 = bx * 64;
    unsigned short* Ys = (g == 0) ? Y0 : (g == 1) ? Y1 : Y2;

    int colb = lane & 15;
    int q8 = (lane >> 4) << 3;
    int rq = (lane >> 4) << 2;
    int arow = m0 + w * 16 + colb;
    bool rok = arow < nrows;

    short8 afr[KT];
    #pragma unroll
    for (int kt = 0; kt < KT; ++kt) {
        short8 z = {0, 0, 0, 0, 0, 0, 0, 0};
        afr[kt] = rok ? *reinterpret_cast<const short8*>(Xb + (size_t)arow * FIN + (kt << 5) + q8) : z;
    }

    for (int nt = 0; nt < NT; ++nt) {
        int n0 = (g * NT + nt) << 5;
        __syncthreads();
        for (int span = tid; span < 32 * F8; span += 256) {
            int r = span / F8, c8 = (span - r * F8) << 3;
            int pr = (r < 16) ? (r << 1) : (((r - 16) << 1) + 1);
            *reinterpret_cast<uint4*>(&Bs[r * SA + c8]) =
                *reinterpret_cast<const uint4*>(WT + (size_t)(n0 + pr) * FIN + c8);
        }
        __syncthreads();

        f32x4 acc0 = {0.f, 0.f, 0.f, 0.f}, acc1 = acc0;
        #pragma unroll
        for (int kt = 0; kt < KT; ++kt) {
            short8 b0 = *reinterpret_cast<const short8*>(&Bs[colb * SA + (kt << 5) + q8]);
            short8 b1 = *reinterpret_cast<const short8*>(&Bs[(colb + 16) * SA + (kt << 5) + q8]);
            acc0 = __builtin_amdgcn_mfma_f32_16x16x32_bf16(afr[kt], b0, acc0, 0, 0, 0);
            acc1 = __builtin_amdgcn_mfma_f32_16x16x32_bf16(afr[kt], b1, acc1, 0, 0, 0);
        }

        int lc = (nt << 5) + (colb << 1);
        #pragma unroll
        for (int r = 0; r < 4; ++r) {
            int orow = m0 + w * 16 + rq + r;
            if (orow < nrows) {
                float sc = (g == 2) ? dinv[orow] : 1.0f;
                unsigned pack = f2bf(acc0[r] * sc) | (f2bf(acc1[r] * sc) << 16);
                *reinterpret_cast<unsigned*>(Ys + (size_t)orow * F + lc) = pack;
            }
        }
    }
}

// ==== D4: merged scatter + layer-1 GEMM (independent inputs, no inter-block sync) ====
__global__ __launch_bounds__(256)
void sg_kernel(const int* __restrict__ src, const int* __restrict__ dst,
               const float* __restrict__ ea,
               const int* __restrict__ rowptr, const int* __restrict__ pcnt,
               int2* __restrict__ csr,
               const unsigned short* __restrict__ Xb, const unsigned short* __restrict__ WT1,
               const float* __restrict__ dinv,
               unsigned short* __restrict__ Y0, unsigned short* __restrict__ Y1,
               unsigned short* __restrict__ Y2) {
    __shared__ alignas(16) unsigned char sm[32768];
    int vb = blockIdx.x;
    if (vb < SCVB) {
        scatter_body(vb, src, dst, ea, rowptr, pcnt, csr, sm);
    } else {
        int v2 = vb - SCVB;
        gemm_body<160, 128>(v2 % GEMM_MB, v2 / GEMM_MB, Xb, WT1, dinv, Y0, Y1, Y2, N_NODES, sm);
    }
}

// ==== layers 2/3 GEMM ====
template<int FIN, int F>
__launch_bounds__(256)
__global__ void cheb_gemm(const unsigned short* __restrict__ Xb, const unsigned short* __restrict__ WT,
                          const float* __restrict__ dinv,
                          unsigned short* __restrict__ Y0, unsigned short* __restrict__ Y1,
                          unsigned short* __restrict__ Y2, int nrows) {
    __shared__ alignas(16) unsigned char sm[32 * (FIN + 8) * 2];
    gemm_body<FIN, F>(blockIdx.x, blockIdx.y, Xb, WT, dinv, Y0, Y1, Y2, nrows, sm);
}

// ============ bf16 CSR gathers: LDS-staged indices + 8-deep load pipeline ============
__device__ __forceinline__ void acc8(float* acc, uint4 p, float wv) {
    acc[0] += wv * bf2f(p.x & 0xFFFFu);
    acc[1] += wv * __uint_as_float(p.x & 0xFFFF0000u);
    acc[2] += wv * bf2f(p.y & 0xFFFFu);
    acc[3] += wv * __uint_as_float(p.y & 0xFFFF0000u);
    acc[4] += wv * bf2f(p.z & 0xFFFFu);
    acc[5] += wv * __uint_as_float(p.z & 0xFFFF0000u);
    acc[6] += wv * bf2f(p.w & 0xFFFFu);
    acc[7] += wv * __uint_as_float(p.w & 0xFFFF0000u);
}

__device__ __forceinline__ void expand8(uint4 p, float* o) {
    o[0] = bf2f(p.x & 0xFFFFu);
    o[1] = __uint_as_float(p.x & 0xFFFF0000u);
    o[2] = bf2f(p.y & 0xFFFFu);
    o[3] = __uint_as_float(p.y & 0xFFFF0000u);
    o[4] = bf2f(p.z & 0xFFFFu);
    o[5] = __uint_as_float(p.z & 0xFFFF0000u);
    o[6] = bf2f(p.w & 0xFFFFu);
    o[7] = __uint_as_float(p.w & 0xFFFF0000u);
}

// MODE 0: U' = dv*(Y - 2*dv*t) ;  MODE 1: relu(Y - dv*t + bias)
template<int F, int MODE>
__launch_bounds__(256)
__global__ void gather_kernel(const unsigned short* __restrict__ X, const int2* __restrict__ csr,
                              const int* __restrict__ rowptr, const float* __restrict__ dinv,
                              const unsigned short* __restrict__ Y, const float* __restrict__ bias,
                              unsigned short* __restrict__ O, int n) {
    constexpr int FQ8 = F >> 3;            // chunks per row: 16/8/4
    constexpr int DPB = 256 / FQ8;         // dsts per block: 16/32/64
    constexpr int CAP = 2048;              // staged edge capacity (16 KB)
    __shared__ int2 scsr[CAP];
    __shared__ int srp[DPB + 1];
    int tid = threadIdx.x;
    int db0 = blockIdx.x * DPB;
    if (tid <= DPB) srp[tid] = rowptr[min(db0 + tid, n)];
    __syncthreads();
    int ebeg = srp[0];
    int ecnt = srp[DPB] - ebeg;
    bool staged = ecnt <= CAP;
    if (staged) {
        for (int i = tid; i < ecnt; i += 256)
            scsr[i] = csr[ebeg + i];
    }
    __syncthreads();

    int d = db0 + tid / FQ8;
    if (d >= n) return;
    int f8 = (tid % FQ8) << 3;
    float acc[8] = {0.f, 0.f, 0.f, 0.f, 0.f, 0.f, 0.f, 0.f};

    if (staged) {
        int beg = srp[tid / FQ8] - ebeg, end = srp[tid / FQ8 + 1] - ebeg;
        int i = beg;
        for (; i + 7 < end; i += 8) {      // 8 independent X-rows in flight
            int2 e0 = scsr[i],     e1 = scsr[i + 1], e2 = scsr[i + 2], e3 = scsr[i + 3];
            int2 e4 = scsr[i + 4], e5 = scsr[i + 5], e6 = scsr[i + 6], e7 = scsr[i + 7];
            uint4 p0 = *reinterpret_cast<const uint4*>(X + (size_t)e0.x * F + f8);
            uint4 p1 = *reinterpret_cast<const uint4*>(X + (size_t)e1.x * F + f8);
            uint4 p2 = *reinterpret_cast<const uint4*>(X + (size_t)e2.x * F + f8);
            uint4 p3 = *reinterpret_cast<const uint4*>(X + (size_t)e3.x * F + f8);
            uint4 p4 = *reinterpret_cast<const uint4*>(X + (size_t)e4.x * F + f8);
            uint4 p5 = *reinterpret_cast<const uint4*>(X + (size_t)e5.x * F + f8);
            uint4 p6 = *reinterpret_cast<const uint4*>(X + (size_t)e6.x * F + f8);
            uint4 p7 = *reinterpret_cast<const uint4*>(X + (size_t)e7.x * F + f8);
            acc8(acc, p0, __int_as_float(e0.y));
            acc8(acc, p1, __int_as_float(e1.y));
            acc8(acc, p2, __int_as_float(e2.y));
            acc8(acc, p3, __int_as_float(e3.y));
            acc8(acc, p4, __int_as_float(e4.y));
            acc8(acc, p5, __int_as_float(e5.y));
            acc8(acc, p6, __int_as_float(e6.y));
            acc8(acc, p7, __int_as_float(e7.y));
        }
        for (; i + 3 < end; i += 4) {
            int2 e0 = scsr[i], e1 = scsr[i + 1], e2 = scsr[i + 2], e3 = scsr[i + 3];
            uint4 p0 = *reinterpret_cast<const uint4*>(X + (size_t)e0.x * F + f8);
            uint4 p1 = *reinterpret_cast<const uint4*>(X + (size_t)e1.x * F + f8);
            uint4 p2 = *reinterpret_cast<const uint4*>(X + (size_t)e2.x * F + f8);
            uint4 p3 = *reinterpret_cast<const uint4*>(X + (size_t)e3.x * F + f8);
            acc8(acc, p0, __int_as_float(e0.y));
            acc8(acc, p1, __int_as_float(e1.y));
            acc8(acc, p2, __int_as_float(e2.y));
            acc8(acc, p3, __int_as_float(e3.y));
        }
        for (; i < end; ++i) {
            int2 e = scsr[i];
            uint4 p = *reinterpret_cast<const uint4*>(X + (size_t)e.x * F + f8);
            acc8(acc, p, __int_as_float(e.y));
        }
    } else {                               // fallback: direct global (never expected)
        int beg = srp[tid / FQ8], end = srp[tid / FQ8 + 1];
        for (int i = beg; i < end; ++i) {
            int2 e = csr[i];
            uint4 p = *reinterpret_cast<const uint4*>(X + (size_t)e.x * F + f8);
            acc8(acc, p, __int_as_float(e.y));
        }
    }

    float y[8];
    expand8(*reinterpret_cast<const uint4*>(Y + (size_t)d * F + f8), y);
    float dv = dinv[d];
    float v[8];
    if (MODE == 0) {
        float dv2 = 2.f * dv;
        #pragma unroll
        for (int j = 0; j < 8; ++j) v[j] = dv * (y[j] - dv2 * acc[j]);
    } else {
        float4 ba = *reinterpret_cast<const float4*>(bias + f8);
        float4 bb = *reinterpret_cast<const float4*>(bias + f8 + 4);
        v[0] = fmaxf(y[0] - dv * acc[0] + ba.x, 0.f);
        v[1] = fmaxf(y[1] - dv * acc[1] + ba.y, 0.f);
        v[2] = fmaxf(y[2] - dv * acc[2] + ba.z, 0.f);
        v[3] = fmaxf(y[3] - dv * acc[3] + ba.w, 0.f);
        v[4] = fmaxf(y[4] - dv * acc[4] + bb.x, 0.f);
        v[5] = fmaxf(y[5] - dv * acc[5] + bb.y, 0.f);
        v[6] = fmaxf(y[6] - dv * acc[6] + bb.z, 0.f);
        v[7] = fmaxf(y[7] - dv * acc[7] + bb.w, 0.f);
    }
    uint4 o;
    o.x = f2bf(v[0]) | (f2bf(v[1]) << 16);
    o.y = f2bf(v[2]) | (f2bf(v[3]) << 16);
    o.z = f2bf(v[4]) | (f2bf(v[5]) << 16);
    o.w = f2bf(v[6]) | (f2bf(v[7]) << 16);
    *reinterpret_cast<uint4*>(O + (size_t)d * F + f8) = o;
}

// ============ pooling + final linear ============
__device__ __forceinline__ int lower_bound_dev(const int* __restrict__ a, int n, int v) {
    int lo = 0, hi = n;
    while (lo < hi) {
        int mid = (lo + hi) >> 1;
        if (a[mid] < v) lo = mid + 1; else hi = mid;
    }
    return lo;
}

__global__ void pool_kernel(const unsigned short* __restrict__ H, const int* __restrict__ batch,
                            const float* __restrict__ Wl, const float* __restrict__ bl,
                            float* __restrict__ out, int n) {
    int g = blockIdx.x;
    int start = lower_bound_dev(batch, n, g);
    int end   = lower_bound_dev(batch, n, g + 1);
    int tid = threadIdx.x;
    int f = tid & 31;
    int sub = tid >> 5;
    float acc = 0.0f;
    for (int i = start + sub; i < end; i += 8)
        acc += bf2f((unsigned)H[(size_t)i * 32 + f]);
    __shared__ float red[256];
    red[tid] = acc;
    __syncthreads();
    if (tid < 128) red[tid] += red[tid + 128];
    __syncthreads();
    if (tid < 64) red[tid] += red[tid + 64];
    __syncthreads();
    if (tid < 32) red[tid] += red[tid + 32];
    __syncthreads();
    if (tid < 2) {
        int cnt = end - start;
        float inv = 1.0f / (float)(cnt > 0 ? cnt : 1);
        float o = bl[tid];
        for (int f2 = 0; f2 < 32; ++f2)
            o += red[f2] * inv * Wl[f2 * 2 + tid];
        out[g * 2 + tid] = o;
    }
}

extern "C" void kernel_launch(void* const* d_in, const int* in_sizes, int n_in,
                              void* d_out, int out_size, void* d_ws, size_t ws_size,
                              hipStream_t stream) {
    const float* x     = (const float*)d_in[0];
    const int*   ei    = (const int*)d_in[1];
    const float* ea    = (const float*)d_in[2];
    const int*   batch = (const int*)d_in[3];
    const float* W1 = (const float*)d_in[4];
    const float* b1 = (const float*)d_in[5];
    const float* W2 = (const float*)d_in[6];
    const float* b2 = (const float*)d_in[7];
    const float* W3 = (const float*)d_in[8];
    const float* b3 = (const float*)d_in[9];
    const float* Wl = (const float*)d_in[10];
    const float* bl = (const float*)d_in[11];
    float* out = (float*)d_out;
    char* ws = (char*)d_ws;

    const int* src = ei;
    const int* dst = ei + N_EDGES;

    size_t off = 0;
    auto alloc = [&](size_t bytes) { char* p = ws + off; off += (bytes + 255) & ~(size_t)255; return p; };
    float* pdeg    = (float*)alloc((size_t)NCX * PN * 4);
    int*   pcnt    = (int*)  alloc((size_t)NCX * PN * 4);
    float* dinv    = (float*)alloc(N_NODES * 4);
    int*   cnt     = (int*)  alloc((size_t)PN * 4);
    int*   partial = (int*)  alloc(SCAN_NB * 4);
    int*   rowptr  = (int*)  alloc((N_NODES + 1) * 4);
    int2*  csr     = (int2*) alloc((size_t)N_EDGES * 8);
    unsigned short* Xb  = (unsigned short*)alloc((size_t)N_NODES * 160 * 2);
    unsigned short* Y0  = (unsigned short*)alloc((size_t)N_NODES * 128 * 2);
    unsigned short* Y1  = (unsigned short*)alloc((size_t)N_NODES * 128 * 2);
    unsigned short* Y2  = (unsigned short*)alloc((size_t)N_NODES * 128 * 2);
    unsigned short* U   = (unsigned short*)alloc((size_t)N_NODES * 128 * 2);
    unsigned short* WT1 = (unsigned short*)alloc((size_t)384 * 160 * 2);
    unsigned short* WT2 = (unsigned short*)alloc((size_t)192 * 128 * 2);
    unsigned short* WT3 = (unsigned short*)alloc((size_t)96 * 64 * 2);

    const int BT = 256;

    // D1: single-pass hist (deg + cnt in one edge scan)
    hist_kernel<<<dim3(NCX, NRY), BT, 0, stream>>>(src, dst, ea, pdeg, pcnt);
    // D2: reduce + conv + wprep (independent virtual blocks)
    rs_kernel<<<SCAN_NB + CONVB + WPREPB, BT, 0, stream>>>(pdeg, pcnt, dinv, cnt, partial,
                                                           x, Xb, W1, W2, W3, WT1, WT2, WT3);
    // D3: final scan -> rowptr
    scan_final_kernel<<<SCAN_NB, BT, 0, stream>>>(cnt, partial, rowptr, N_NODES);
    // D4: scatter + layer-1 GEMM merged
    sg_kernel<<<SCVB + 3 * GEMM_MB, BT, 0, stream>>>(src, dst, ea, rowptr, pcnt, csr,
                                                     Xb, WT1, dinv, Y0, Y1, Y2);

    dim3 ggrid(GEMM_MB, 3);
    auto gb = [&](int F) { int DPB = 256 / (F / 8); return (N_NODES + DPB - 1) / DPB; };

    gather_kernel<128, 0><<<gb(128), BT, 0, stream>>>(Y2, csr, rowptr, dinv, Y1, nullptr, U, N_NODES);
    gather_kernel<128, 1><<<gb(128), BT, 0, stream>>>(U, csr, rowptr, dinv, Y0, b1, Xb, N_NODES);

    cheb_gemm<128, 64><<<ggrid, BT, 0, stream>>>(Xb, WT2, dinv, Y0, Y1, Y2, N_NODES);
    gather_kernel<64, 0><<<gb(64), BT, 0, stream>>>(Y2, csr, rowptr, dinv, Y1, nullptr, U, N_NODES);
    gather_kernel<64, 1><<<gb(64), BT, 0, stream>>>(U, csr, rowptr, dinv, Y0, b2, Xb, N_NODES);

    cheb_gemm<64, 32><<<ggrid, BT, 0, stream>>>(Xb, WT3, dinv, Y0, Y1, Y2, N_NODES);
    gather_kernel<32, 0><<<gb(32), BT, 0, stream>>>(Y2, csr, rowptr, dinv, Y1, nullptr, U, N_NODES);
    gather_kernel<32, 1><<<gb(32), BT, 0, stream>>>(U, csr, rowptr, dinv, Y0, b3, Xb, N_NODES);

    pool_kernel<<<NUM_G, BT, 0, stream>>>(Xb, batch, Wl, bl, out, N_NODES);
}

// Round 17
// 310.711 us; speedup vs baseline: 1.0176x; 1.0176x over previous
//
#include <hip/hip_runtime.h>

#define N_NODES 50000
#define N_EDGES 500000
#define NUM_G   128
#define SCAN_NB 49               // ceil(50176/1024)
#define PN      (SCAN_NB * 1024) // 50176 padded node count
#define NCX     64               // edge chunks
#define ECH     7813             // 64*7813 >= 500000
#define RNG     8192             // nodes per LDS range (32 KB)
#define NRY     7                // 7*8192 >= PN
#define HVB     (2 * NCX * NRY)  // 896 hist virtual blocks
#define CONVB   7813             // conv blocks (50000*160/4 / 256)
#define WPREPB  360
#define SCVB    (NCX * NRY)      // 448 scatter virtual blocks
#define GEMM_MB 782              // (50000+63)/64

typedef __attribute__((ext_vector_type(8))) short short8;
typedef __attribute__((ext_vector_type(4))) float f32x4;

__device__ __forceinline__ unsigned f2bf(float x) {
    unsigned u = __float_as_uint(x);
    return (u + 0x7FFFu + ((u >> 16) & 1u)) >> 16;   // RNE
}
__device__ __forceinline__ float bf2f(unsigned h) {
    return __uint_as_float(h << 16);
}

// ============ D1: hist partials + fp32->bf16 conv + weight prep (one dispatch) ============
__device__ __forceinline__ void wprep_one(const float* __restrict__ W, unsigned short* __restrict__ WT,
                                          int t, int FIN, int F) {
    int n = t / FIN, k = t - n * FIN;
    int sel = n / F, c = n - sel * F;
    float v;
    if (sel == 0) v = W[(size_t)k * F + c] - W[(size_t)2 * FIN * F + (size_t)k * F + c];
    else          v = W[(size_t)sel * FIN * F + (size_t)k * F + c];
    WT[t] = (unsigned short)f2bf(v);
}

__global__ __launch_bounds__(256)
void prep_kernel(const int* __restrict__ src, const int* __restrict__ dst,
                 const float* __restrict__ ea,
                 float* __restrict__ pdeg, int* __restrict__ pcnt,
                 const float* __restrict__ x, unsigned short* __restrict__ Xb,
                 const float* __restrict__ W1, const float* __restrict__ W2,
                 const float* __restrict__ W3,
                 unsigned short* __restrict__ WT1, unsigned short* __restrict__ WT2,
                 unsigned short* __restrict__ WT3) {
    __shared__ unsigned lh[RNG];
    int vb = blockIdx.x, tid = threadIdx.x;
    if (vb < HVB) {
        bool isdeg = vb < NCX * NRY;
        int v2 = isdeg ? vb : vb - NCX * NRY;
        int xk = v2 & 63, y = v2 >> 6;
        int base = y * RNG;
        for (int i = tid; i < RNG; i += 256) lh[i] = 0u;
        __syncthreads();
        int e0 = xk * ECH, e1 = min(e0 + ECH, N_EDGES);
        if (isdeg) {
            for (int e = e0 + tid; e < e1; e += 256) {
                int s = src[e];
                if ((unsigned)(s - base) < RNG) atomicAdd((float*)&lh[s - base], ea[e]);
            }
        } else {
            for (int e = e0 + tid; e < e1; e += 256) {
                int d = dst[e];
                if ((unsigned)(d - base) < RNG) atomicAdd((int*)&lh[d - base], 1);
            }
        }
        __syncthreads();
        if (isdeg) {
            for (int i = tid; i < RNG; i += 256) {
                int n = base + i;
                if (n < PN) pdeg[(size_t)xk * PN + n] = ((float*)lh)[i];
            }
        } else {
            for (int i = tid; i < RNG; i += 256) {
                int n = base + i;
                if (n < PN) pcnt[(size_t)xk * PN + n] = ((int*)lh)[i];
            }
        }
    } else if (vb < HVB + CONVB) {
        int t = (vb - HVB) * 256 + tid;
        if (t < N_NODES * 160 / 4) {
            float4 v = reinterpret_cast<const float4*>(x)[t];
            ushort4 r;
            r.x = (unsigned short)f2bf(v.x);
            r.y = (unsigned short)f2bf(v.y);
            r.z = (unsigned short)f2bf(v.z);
            r.w = (unsigned short)f2bf(v.w);
            *reinterpret_cast<ushort4*>(Xb + (size_t)t * 4) = r;
        }
    } else {
        int t = (vb - HVB - CONVB) * 256 + tid;
        if (t < 61440)      wprep_one(W1, WT1, t, 160, 128);
        else if (t < 86016) wprep_one(W2, WT2, t - 61440, 128, 64);
        else if (t < 92160) wprep_one(W3, WT3, t - 86016, 64, 32);
    }
}

// ==== D2: reduce partials -> dinv, cnt; pcnt -> exclusive chunk-prefix; block sums ====
__global__ __launch_bounds__(256)
void reduce_scan_kernel(const float* __restrict__ pdeg, int* __restrict__ pcnt,
                        float* __restrict__ dinv, int* __restrict__ cnt,
                        int* __restrict__ partial) {
    int b = blockIdx.x, t = threadIdx.x;
    int i0 = b * 1024 + t * 4;
    float d0 = 0.f, d1 = 0.f, d2 = 0.f, d3 = 0.f;
    int r0 = 0, r1 = 0, r2 = 0, r3 = 0;
    for (int x = 0; x < NCX; ++x) {
        float4 pv = *reinterpret_cast<const float4*>(pdeg + (size_t)x * PN + i0);
        int4   cv = *reinterpret_cast<const int4*>(pcnt + (size_t)x * PN + i0);
        *reinterpret_cast<int4*>(pcnt + (size_t)x * PN + i0) = make_int4(r0, r1, r2, r3);
        d0 += pv.x; d1 += pv.y; d2 += pv.z; d3 += pv.w;
        r0 += cv.x; r1 += cv.y; r2 += cv.z; r3 += cv.w;
    }
    float dd[4] = {d0, d1, d2, d3};
    int   rr[4] = {r0, r1, r2, r3};
    int s = 0;
    #pragma unroll
    for (int j = 0; j < 4; ++j) {
        int n = i0 + j;
        if (n < N_NODES) {
            float dv = dd[j], r = 0.f;
            if (dv > 0.f) {
                r = rsqrtf(dv);
                r = r * (1.5f - 0.5f * dv * r * r);   // Newton refine to ~fp32 exact
            }
            dinv[n] = r;
            cnt[n] = rr[j];
            s += rr[j];
        } else {
            cnt[n] = 0;
        }
    }
    __shared__ int red[256];
    red[t] = s;
    __syncthreads();
    for (int off = 128; off > 0; off >>= 1) {
        if (t < off) red[t] += red[t + off];
        __syncthreads();
    }
    if (t == 0) partial[b] = red[0];
}

// ==== D3: final scan -> rowptr (each block redundantly wave-scans the 49 partials) ====
__global__ __launch_bounds__(256)
void scan_final_kernel(const int* __restrict__ cnt, const int* __restrict__ partial,
                       int* __restrict__ rowptr, int n) {
    int b = blockIdx.x, t = threadIdx.x;
    __shared__ int red[256];
    __shared__ int sh_off, sh_tot;
    if (t < 64) {
        int orig = (t < SCAN_NB) ? partial[t] : 0;
        int v = orig;
        #pragma unroll
        for (int off = 1; off < 64; off <<= 1) {
            int u = __shfl_up(v, off, 64);
            if (t >= off) v += u;
        }
        if (t == b) sh_off = v - orig;            // this block's exclusive offset (b < 49 <= 63)
        if (t == SCAN_NB - 1) sh_tot = v;         // grand total
    }
    __syncthreads();
    int4 v = reinterpret_cast<const int4*>(cnt)[b * 256 + t];
    int s = v.x + v.y + v.z + v.w;
    red[t] = s;
    __syncthreads();
    for (int off = 1; off < 256; off <<= 1) {
        int u = (t >= off) ? red[t - off] : 0;
        __syncthreads();
        red[t] += u;
        __syncthreads();
    }
    int excl = sh_off + ((t == 0) ? 0 : red[t - 1]);
    int i0 = b * 1024 + t * 4;
    if (i0 < n)     rowptr[i0]     = excl;
    if (i0 + 1 < n) rowptr[i0 + 1] = excl + v.x;
    if (i0 + 2 < n) rowptr[i0 + 2] = excl + v.x + v.y;
    if (i0 + 3 < n) rowptr[i0 + 3] = excl + v.x + v.y + v.z;
    if (b == SCAN_NB - 1 && t == 0) rowptr[n] = sh_tot;
}

// ==== shared bodies for the merged D4 dispatch ====
__device__ void scatter_body(int vb, const int* __restrict__ src, const int* __restrict__ dst,
                             const float* __restrict__ ea,
                             const int* __restrict__ rowptr, const int* __restrict__ pcnt,
                             int2* __restrict__ csr, unsigned char* smraw) {
    int* cursor = (int*)smraw;
    int tid = threadIdx.x;
    int x = vb & 63, y = vb >> 6;
    int base = y * RNG;
    for (int i = tid; i < RNG; i += 256) {
        int n = base + i;
        cursor[i] = (n < N_NODES) ? (rowptr[n] + pcnt[(size_t)x * PN + n]) : 0;
    }
    __syncthreads();
    int e0 = x * ECH, e1 = min(e0 + ECH, N_EDGES);
    for (int e = e0 + tid; e < e1; e += 256) {
        int d = dst[e];
        if ((unsigned)(d - base) < RNG) {
            int pos = atomicAdd(&cursor[d - base], 1);   // LDS atomic
            int2 ew;
            ew.x = src[e];
            ew.y = __float_as_int(ea[e]);
            csr[pos] = ew;
        }
    }
}

template<int FIN, int F>
__device__ void gemm_body(int bx, int g, const unsigned short* __restrict__ Xb,
                          const unsigned short* __restrict__ WT, const float* __restrict__ dinv,
                          unsigned short* __restrict__ Y0, unsigned short* __restrict__ Y1,
                          unsigned short* __restrict__ Y2, int nrows, unsigned char* smraw) {
    constexpr int KT = FIN / 32;
    constexpr int NT = F / 32;
    constexpr int SA = FIN + 8;
    constexpr int F8 = FIN / 8;
    short* Bs = (short*)smraw;

    int tid = threadIdx.x;
    int lane = tid & 63, w = tid >> 6;
    int m0 = bx * 64;
    unsigned short* Ys = (g == 0) ? Y0 : (g == 1) ? Y1 : Y2;

    int colb = lane & 15;
    int q8 = (lane >> 4) << 3;
    int rq = (lane >> 4) << 2;
    int arow = m0 + w * 16 + colb;
    bool rok = arow < nrows;

    short8 afr[KT];
    #pragma unroll
    for (int kt = 0; kt < KT; ++kt) {
        short8 z = {0, 0, 0, 0, 0, 0, 0, 0};
        afr[kt] = rok ? *reinterpret_cast<const short8*>(Xb + (size_t)arow * FIN + (kt << 5) + q8) : z;
    }

    for (int nt = 0; nt < NT; ++nt) {
        int n0 = (g * NT + nt) << 5;
        __syncthreads();
        for (int span = tid; span < 32 * F8; span += 256) {
            int r = span / F8, c8 = (span - r * F8) << 3;
            int pr = (r < 16) ? (r << 1) : (((r - 16) << 1) + 1);
            *reinterpret_cast<uint4*>(&Bs[r * SA + c8]) =
                *reinterpret_cast<const uint4*>(WT + (size_t)(n0 + pr) * FIN + c8);
        }
        __syncthreads();

        f32x4 acc0 = {0.f, 0.f, 0.f, 0.f}, acc1 = acc0;
        #pragma unroll
        for (int kt = 0; kt < KT; ++kt) {
            short8 b0 = *reinterpret_cast<const short8*>(&Bs[colb * SA + (kt << 5) + q8]);
            short8 b1 = *reinterpret_cast<const short8*>(&Bs[(colb + 16) * SA + (kt << 5) + q8]);
            acc0 = __builtin_amdgcn_mfma_f32_16x16x32_bf16(afr[kt], b0, acc0, 0, 0, 0);
            acc1 = __builtin_amdgcn_mfma_f32_16x16x32_bf16(afr[kt], b1, acc1, 0, 0, 0);
        }

        int lc = (nt << 5) + (colb << 1);
        #pragma unroll
        for (int r = 0; r < 4; ++r) {
            int orow = m0 + w * 16 + rq + r;
            if (orow < nrows) {
                float sc = (g == 2) ? dinv[orow] : 1.0f;
                unsigned pack = f2bf(acc0[r] * sc) | (f2bf(acc1[r] * sc) << 16);
                *reinterpret_cast<unsigned*>(Ys + (size_t)orow * F + lc) = pack;
            }
        }
    }
}

// ==== D4: merged scatter + layer-1 GEMM (independent inputs, no inter-block sync) ====
__global__ __launch_bounds__(256)
void sg_kernel(const int* __restrict__ src, const int* __restrict__ dst,
               const float* __restrict__ ea,
               const int* __restrict__ rowptr, const int* __restrict__ pcnt,
               int2* __restrict__ csr,
               const unsigned short* __restrict__ Xb, const unsigned short* __restrict__ WT1,
               const float* __restrict__ dinv,
               unsigned short* __restrict__ Y0, unsigned short* __restrict__ Y1,
               unsigned short* __restrict__ Y2) {
    __shared__ alignas(16) unsigned char sm[32768];
    int vb = blockIdx.x;
    if (vb < SCVB) {
        scatter_body(vb, src, dst, ea, rowptr, pcnt, csr, sm);
    } else {
        int v2 = vb - SCVB;
        gemm_body<160, 128>(v2 % GEMM_MB, v2 / GEMM_MB, Xb, WT1, dinv, Y0, Y1, Y2, N_NODES, sm);
    }
}

// ==== layers 2/3 GEMM ====
template<int FIN, int F>
__launch_bounds__(256)
__global__ void cheb_gemm(const unsigned short* __restrict__ Xb, const unsigned short* __restrict__ WT,
                          const float* __restrict__ dinv,
                          unsigned short* __restrict__ Y0, unsigned short* __restrict__ Y1,
                          unsigned short* __restrict__ Y2, int nrows) {
    __shared__ alignas(16) unsigned char sm[32 * (FIN + 8) * 2];
    gemm_body<FIN, F>(blockIdx.x, blockIdx.y, Xb, WT, dinv, Y0, Y1, Y2, nrows, sm);
}

// ============ bf16 CSR gathers: LDS-staged indices + 8-deep load pipeline ============
__device__ __forceinline__ void acc8(float* acc, uint4 p, float wv) {
    acc[0] += wv * bf2f(p.x & 0xFFFFu);
    acc[1] += wv * __uint_as_float(p.x & 0xFFFF0000u);
    acc[2] += wv * bf2f(p.y & 0xFFFFu);
    acc[3] += wv * __uint_as_float(p.y & 0xFFFF0000u);
    acc[4] += wv * bf2f(p.z & 0xFFFFu);
    acc[5] += wv * __uint_as_float(p.z & 0xFFFF0000u);
    acc[6] += wv * bf2f(p.w & 0xFFFFu);
    acc[7] += wv * __uint_as_float(p.w & 0xFFFF0000u);
}

__device__ __forceinline__ void expand8(uint4 p, float* o) {
    o[0] = bf2f(p.x & 0xFFFFu);
    o[1] = __uint_as_float(p.x & 0xFFFF0000u);
    o[2] = bf2f(p.y & 0xFFFFu);
    o[3] = __uint_as_float(p.y & 0xFFFF0000u);
    o[4] = bf2f(p.z & 0xFFFFu);
    o[5] = __uint_as_float(p.z & 0xFFFF0000u);
    o[6] = bf2f(p.w & 0xFFFFu);
    o[7] = __uint_as_float(p.w & 0xFFFF0000u);
}

// MODE 0: U' = dv*(Y - 2*dv*t) ;  MODE 1: relu(Y - dv*t + bias)
template<int F, int MODE>
__launch_bounds__(256)
__global__ void gather_kernel(const unsigned short* __restrict__ X, const int2* __restrict__ csr,
                              const int* __restrict__ rowptr, const float* __restrict__ dinv,
                              const unsigned short* __restrict__ Y, const float* __restrict__ bias,
                              unsigned short* __restrict__ O, int n) {
    constexpr int FQ8 = F >> 3;            // chunks per row: 16/8/4
    constexpr int DPB = 256 / FQ8;         // dsts per block: 16/32/64
    constexpr int CAP = 2048;              // staged edge capacity (16 KB)
    __shared__ int2 scsr[CAP];
    __shared__ int srp[DPB + 1];
    int tid = threadIdx.x;
    int db0 = blockIdx.x * DPB;
    if (tid <= DPB) srp[tid] = rowptr[min(db0 + tid, n)];
    __syncthreads();
    int ebeg = srp[0];
    int ecnt = srp[DPB] - ebeg;
    bool staged = ecnt <= CAP;
    if (staged) {
        for (int i = tid; i < ecnt; i += 256)
            scsr[i] = csr[ebeg + i];
    }
    __syncthreads();

    int d = db0 + tid / FQ8;
    if (d >= n) return;
    int f8 = (tid % FQ8) << 3;
    float acc[8] = {0.f, 0.f, 0.f, 0.f, 0.f, 0.f, 0.f, 0.f};

    if (staged) {
        int beg = srp[tid / FQ8] - ebeg, end = srp[tid / FQ8 + 1] - ebeg;
        int i = beg;
        for (; i + 7 < end; i += 8) {      // 8 independent X-rows in flight
            int2 e0 = scsr[i],     e1 = scsr[i + 1], e2 = scsr[i + 2], e3 = scsr[i + 3];
            int2 e4 = scsr[i + 4], e5 = scsr[i + 5], e6 = scsr[i + 6], e7 = scsr[i + 7];
            uint4 p0 = *reinterpret_cast<const uint4*>(X + (size_t)e0.x * F + f8);
            uint4 p1 = *reinterpret_cast<const uint4*>(X + (size_t)e1.x * F + f8);
            uint4 p2 = *reinterpret_cast<const uint4*>(X + (size_t)e2.x * F + f8);
            uint4 p3 = *reinterpret_cast<const uint4*>(X + (size_t)e3.x * F + f8);
            uint4 p4 = *reinterpret_cast<const uint4*>(X + (size_t)e4.x * F + f8);
            uint4 p5 = *reinterpret_cast<const uint4*>(X + (size_t)e5.x * F + f8);
            uint4 p6 = *reinterpret_cast<const uint4*>(X + (size_t)e6.x * F + f8);
            uint4 p7 = *reinterpret_cast<const uint4*>(X + (size_t)e7.x * F + f8);
            acc8(acc, p0, __int_as_float(e0.y));
            acc8(acc, p1, __int_as_float(e1.y));
            acc8(acc, p2, __int_as_float(e2.y));
            acc8(acc, p3, __int_as_float(e3.y));
            acc8(acc, p4, __int_as_float(e4.y));
            acc8(acc, p5, __int_as_float(e5.y));
            acc8(acc, p6, __int_as_float(e6.y));
            acc8(acc, p7, __int_as_float(e7.y));
        }
        for (; i + 3 < end; i += 4) {
            int2 e0 = scsr[i], e1 = scsr[i + 1], e2 = scsr[i + 2], e3 = scsr[i + 3];
            uint4 p0 = *reinterpret_cast<const uint4*>(X + (size_t)e0.x * F + f8);
            uint4 p1 = *reinterpret_cast<const uint4*>(X + (size_t)e1.x * F + f8);
            uint4 p2 = *reinterpret_cast<const uint4*>(X + (size_t)e2.x * F + f8);
            uint4 p3 = *reinterpret_cast<const uint4*>(X + (size_t)e3.x * F + f8);
            acc8(acc, p0, __int_as_float(e0.y));
            acc8(acc, p1, __int_as_float(e1.y));
            acc8(acc, p2, __int_as_float(e2.y));
            acc8(acc, p3, __int_as_float(e3.y));
        }
        for (; i < end; ++i) {
            int2 e = scsr[i];
            uint4 p = *reinterpret_cast<const uint4*>(X + (size_t)e.x * F + f8);
            acc8(acc, p, __int_as_float(e.y));
        }
    } else {                               // fallback: direct global (never expected)
        int beg = srp[tid / FQ8], end = srp[tid / FQ8 + 1];
        for (int i = beg; i < end; ++i) {
            int2 e = csr[i];
            uint4 p = *reinterpret_cast<const uint4*>(X + (size_t)e.x * F + f8);
            acc8(acc, p, __int_as_float(e.y));
        }
    }

    float y[8];
    expand8(*reinterpret_cast<const uint4*>(Y + (size_t)d * F + f8), y);
    float dv = dinv[d];
    float v[8];
    if (MODE == 0) {
        float dv2 = 2.f * dv;
        #pragma unroll
        for (int j = 0; j < 8; ++j) v[j] = dv * (y[j] - dv2 * acc[j]);
    } else {
        float4 ba = *reinterpret_cast<const float4*>(bias + f8);
        float4 bb = *reinterpret_cast<const float4*>(bias + f8 + 4);
        v[0] = fmaxf(y[0] - dv * acc[0] + ba.x, 0.f);
        v[1] = fmaxf(y[1] - dv * acc[1] + ba.y, 0.f);
        v[2] = fmaxf(y[2] - dv * acc[2] + ba.z, 0.f);
        v[3] = fmaxf(y[3] - dv * acc[3] + ba.w, 0.f);
        v[4] = fmaxf(y[4] - dv * acc[4] + bb.x, 0.f);
        v[5] = fmaxf(y[5] - dv * acc[5] + bb.y, 0.f);
        v[6] = fmaxf(y[6] - dv * acc[6] + bb.z, 0.f);
        v[7] = fmaxf(y[7] - dv * acc[7] + bb.w, 0.f);
    }
    uint4 o;
    o.x = f2bf(v[0]) | (f2bf(v[1]) << 16);
    o.y = f2bf(v[2]) | (f2bf(v[3]) << 16);
    o.z = f2bf(v[4]) | (f2bf(v[5]) << 16);
    o.w = f2bf(v[6]) | (f2bf(v[7]) << 16);
    *reinterpret_cast<uint4*>(O + (size_t)d * F + f8) = o;
}

// ============ pooling + final linear ============
__device__ __forceinline__ int lower_bound_dev(const int* __restrict__ a, int n, int v) {
    int lo = 0, hi = n;
    while (lo < hi) {
        int mid = (lo + hi) >> 1;
        if (a[mid] < v) lo = mid + 1; else hi = mid;
    }
    return lo;
}

__global__ void pool_kernel(const unsigned short* __restrict__ H, const int* __restrict__ batch,
                            const float* __restrict__ Wl, const float* __restrict__ bl,
                            float* __restrict__ out, int n) {
    int g = blockIdx.x;
    int start = lower_bound_dev(batch, n, g);
    int end   = lower_bound_dev(batch, n, g + 1);
    int tid = threadIdx.x;
    int f = tid & 31;
    int sub = tid >> 5;
    float acc = 0.0f;
    for (int i = start + sub; i < end; i += 8)
        acc += bf2f((unsigned)H[(size_t)i * 32 + f]);
    __shared__ float red[256];
    red[tid] = acc;
    __syncthreads();
    if (tid < 128) red[tid] += red[tid + 128];
    __syncthreads();
    if (tid < 64) red[tid] += red[tid + 64];
    __syncthreads();
    if (tid < 32) red[tid] += red[tid + 32];
    __syncthreads();
    if (tid < 2) {
        int cnt = end - start;
        float inv = 1.0f / (float)(cnt > 0 ? cnt : 1);
        float o = bl[tid];
        for (int f2 = 0; f2 < 32; ++f2)
            o += red[f2] * inv * Wl[f2 * 2 + tid];
        out[g * 2 + tid] = o;
    }
}

extern "C" void kernel_launch(void* const* d_in, const int* in_sizes, int n_in,
                              void* d_out, int out_size, void* d_ws, size_t ws_size,
                              hipStream_t stream) {
    const float* x     = (const float*)d_in[0];
    const int*   ei    = (const int*)d_in[1];
    const float* ea    = (const float*)d_in[2];
    const int*   batch = (const int*)d_in[3];
    const float* W1 = (const float*)d_in[4];
    const float* b1 = (const float*)d_in[5];
    const float* W2 = (const float*)d_in[6];
    const float* b2 = (const float*)d_in[7];
    const float* W3 = (const float*)d_in[8];
    const float* b3 = (const float*)d_in[9];
    const float* Wl = (const float*)d_in[10];
    const float* bl = (const float*)d_in[11];
    float* out = (float*)d_out;
    char* ws = (char*)d_ws;

    const int* src = ei;
    const int* dst = ei + N_EDGES;

    size_t off = 0;
    auto alloc = [&](size_t bytes) { char* p = ws + off; off += (bytes + 255) & ~(size_t)255; return p; };
    float* pdeg    = (float*)alloc((size_t)NCX * PN * 4);
    int*   pcnt    = (int*)  alloc((size_t)NCX * PN * 4);
    float* dinv    = (float*)alloc(N_NODES * 4);
    int*   cnt     = (int*)  alloc((size_t)PN * 4);
    int*   partial = (int*)  alloc(SCAN_NB * 4);
    int*   rowptr  = (int*)  alloc((N_NODES + 1) * 4);
    int2*  csr     = (int2*) alloc((size_t)N_EDGES * 8);
    unsigned short* Xb  = (unsigned short*)alloc((size_t)N_NODES * 160 * 2);
    unsigned short* Y0  = (unsigned short*)alloc((size_t)N_NODES * 128 * 2);
    unsigned short* Y1  = (unsigned short*)alloc((size_t)N_NODES * 128 * 2);
    unsigned short* Y2  = (unsigned short*)alloc((size_t)N_NODES * 128 * 2);
    unsigned short* U   = (unsigned short*)alloc((size_t)N_NODES * 128 * 2);
    unsigned short* WT1 = (unsigned short*)alloc((size_t)384 * 160 * 2);
    unsigned short* WT2 = (unsigned short*)alloc((size_t)192 * 128 * 2);
    unsigned short* WT3 = (unsigned short*)alloc((size_t)96 * 64 * 2);

    const int BT = 256;

    // D1: hist + conv + wprep
    prep_kernel<<<HVB + CONVB + WPREPB, BT, 0, stream>>>(src, dst, ea, pdeg, pcnt,
                                                         x, Xb, W1, W2, W3, WT1, WT2, WT3);
    // D2: reduce + block sums
    reduce_scan_kernel<<<SCAN_NB, BT, 0, stream>>>(pdeg, pcnt, dinv, cnt, partial);
    // D3: final scan -> rowptr (offsets computed redundantly per block)
    scan_final_kernel<<<SCAN_NB, BT, 0, stream>>>(cnt, partial, rowptr, N_NODES);
    // D4: scatter + layer-1 GEMM merged
    sg_kernel<<<SCVB + 3 * GEMM_MB, BT, 0, stream>>>(src, dst, ea, rowptr, pcnt, csr,
                                                     Xb, WT1, dinv, Y0, Y1, Y2);

    dim3 ggrid(GEMM_MB, 3);
    auto gb = [&](int F) { int DPB = 256 / (F / 8); return (N_NODES + DPB - 1) / DPB; };

    gather_kernel<128, 0><<<gb(128), BT, 0, stream>>>(Y2, csr, rowptr, dinv, Y1, nullptr, U, N_NODES);
    gather_kernel<128, 1><<<gb(128), BT, 0, stream>>>(U, csr, rowptr, dinv, Y0, b1, Xb, N_NODES);

    cheb_gemm<128, 64><<<ggrid, BT, 0, stream>>>(Xb, WT2, dinv, Y0, Y1, Y2, N_NODES);
    gather_kernel<64, 0><<<gb(64), BT, 0, stream>>>(Y2, csr, rowptr, dinv, Y1, nullptr, U, N_NODES);
    gather_kernel<64, 1><<<gb(64), BT, 0, stream>>>(U, csr, rowptr, dinv, Y0, b2, Xb, N_NODES);

    cheb_gemm<64, 32><<<ggrid, BT, 0, stream>>>(Xb, WT3, dinv, Y0, Y1, Y2, N_NODES);
    gather_kernel<32, 0><<<gb(32), BT, 0, stream>>>(Y2, csr, rowptr, dinv, Y1, nullptr, U, N_NODES);
    gather_kernel<32, 1><<<gb(32), BT, 0, stream>>>(U, csr, rowptr, dinv, Y0, b3, Xb, N_NODES);

    pool_kernel<<<NUM_G, BT, 0, stream>>>(Xb, batch, Wl, bl, out, N_NODES);
}